// Round 4
// baseline (119.598 us; speedup 1.0000x reference)
//
#include <hip/hip_runtime.h>
#include <hip/hip_bf16.h>

typedef unsigned short u16;
typedef __attribute__((ext_vector_type(8))) short short8;
typedef __attribute__((ext_vector_type(4))) float f32x4;

#define NROWS 4096
#define DIM   512
#define TINV  10.0f   // 1/temperature
#define NTILE 32      // 4096/128
#define NBLK  528     // NTILE*(NTILE+1)/2

// round-to-nearest-even f32 -> bf16 bits
__device__ __forceinline__ u16 f2bf(float x) {
    unsigned u = __float_as_uint(x);
    unsigned r = (u + 0x7FFFu + ((u >> 16) & 1u)) >> 16;
    return (u16)r;
}

// ---------------------------------------------------------------------------
// Kernel 1: L2-normalize rows -> bf16; zero S accumulator and done-counter.
// grid = 1024 x 256 (4 rows/block, 1 wave/row)
// ---------------------------------------------------------------------------
__global__ __launch_bounds__(256) void k_norm(const float* __restrict__ in,
                                              u16* __restrict__ out,
                                              float* __restrict__ S,
                                              unsigned* __restrict__ ctr) {
    const int row  = blockIdx.x * 4 + (threadIdx.x >> 6);
    const int lane = threadIdx.x & 63;
    if (threadIdx.x < 4) S[blockIdx.x * 4 + threadIdx.x] = 0.f;
    if (blockIdx.x == 0 && threadIdx.x == 0) *ctr = 0u;

    const float* rp = in + (size_t)row * DIM;
    float4 v0 = ((const float4*)rp)[lane];
    float4 v1 = ((const float4*)rp)[lane + 64];

    float ssq = v0.x*v0.x + v0.y*v0.y + v0.z*v0.z + v0.w*v0.w
              + v1.x*v1.x + v1.y*v1.y + v1.z*v1.z + v1.w*v1.w;
    #pragma unroll
    for (int m = 32; m; m >>= 1) ssq += __shfl_xor(ssq, m);

    const float scale = 1.0f / fmaxf(sqrtf(ssq), 1e-12f);

    u16* op = out + (size_t)row * DIM;
    ((ushort4*)op)[lane] = make_ushort4(
        f2bf(v0.x * scale), f2bf(v0.y * scale),
        f2bf(v0.z * scale), f2bf(v0.w * scale));
    ((ushort4*)op)[lane + 64] = make_ushort4(
        f2bf(v1.x * scale), f2bf(v1.y * scale),
        f2bf(v1.z * scale), f2bf(v1.w * scale));
}

// ---------------------------------------------------------------------------
// Kernel 2: upper-triangular tiles of sim = f f^T (528 blocks, 1D grid),
// fused epilogue (exp/row-col sums/positive extraction) and fused final
// reduction in the last block to finish (threadfence + done-counter).
// BK=64, XOR-swizzled LDS (chunk ^= row&7), pre-swizzled global source,
// linear global_load_lds dest, swizzled ds_read_b128.   [m97/m173 pattern]
// ---------------------------------------------------------------------------
__device__ __forceinline__ void gload_lds16(const u16* g, u16* l) {
    __builtin_amdgcn_global_load_lds(
        (const __attribute__((address_space(1))) void*)g,
        (__attribute__((address_space(3))) void*)l, 16, 0, 0);
}

__global__ __launch_bounds__(256) void k_gemm(const u16* __restrict__ fb,
                                              float* __restrict__ S,
                                              float* __restrict__ P,
                                              unsigned* __restrict__ ctr,
                                              float* __restrict__ out) {
    // --- decode triangular tile index: off(br) = br*(65-br)/2 ---
    const int t = blockIdx.x;
    int br = (int)((65.0f - sqrtf(4225.0f - 8.0f * (float)t)) * 0.5f);
    br = br < 0 ? 0 : (br > 31 ? 31 : br);
    while (br * (65 - br) / 2 > t) --br;
    while ((br + 1) * (64 - br) / 2 <= t) ++br;   // off(br+1) = (br+1)*(64-br)/2
    const int bc = br + (t - br * (65 - br) / 2);

    const bool diag = (br == bc);
    const bool posT = (bc == (br ^ 16));       // tile holding positive pairs

    __shared__ u16 lA[128 * 64];
    __shared__ u16 lB[128 * 64];
    __shared__ unsigned s_done;
    __shared__ float red[4];

    const int tid  = threadIdx.x;
    const int lane = tid & 63;
    const int wid  = tid >> 6;
    const int wr   = wid >> 1;
    const int wc   = wid & 1;
    const int brow = br * 128;
    const int bcol = bc * 128;
    const int lr   = lane & 15;
    const int kg   = lane >> 4;

    f32x4 acc[4][4];
    #pragma unroll
    for (int m = 0; m < 4; ++m)
        #pragma unroll
        for (int n = 0; n < 4; ++n)
            acc[m][n] = (f32x4){0.f, 0.f, 0.f, 0.f};

    const u16* Bsrc = diag ? lA : lB;

    for (int kk = 0; kk < DIM; kk += 64) {
        #pragma unroll
        for (int i = 0; i < 4; ++i) {
            const int q  = tid + i * 256;        // chunk id 0..1023
            const int r  = q >> 3;               // tile row
            const int c  = q & 7;                // dest chunk col
            const int sc = c ^ (r & 7);          // swizzled source chunk
            gload_lds16(fb + (size_t)(brow + r) * DIM + kk + sc * 8, lA + q * 8);
        }
        if (!diag) {
            #pragma unroll
            for (int i = 0; i < 4; ++i) {
                const int q  = tid + i * 256;
                const int r  = q >> 3;
                const int c  = q & 7;
                const int sc = c ^ (r & 7);
                gload_lds16(fb + (size_t)(bcol + r) * DIM + kk + sc * 8, lB + q * 8);
            }
        }
        __syncthreads();

        short8 a[4][2], b[4][2];
        #pragma unroll
        for (int m = 0; m < 4; ++m) {
            const int row = wr * 64 + m * 16 + lr;
            #pragma unroll
            for (int ks = 0; ks < 2; ++ks)
                a[m][ks] = *(const short8*)
                    &lA[row * 64 + (((ks * 4 + kg) ^ (row & 7)) * 8)];
        }
        #pragma unroll
        for (int n = 0; n < 4; ++n) {
            const int row = wc * 64 + n * 16 + lr;
            #pragma unroll
            for (int ks = 0; ks < 2; ++ks)
                b[n][ks] = *(const short8*)
                    &Bsrc[row * 64 + (((ks * 4 + kg) ^ (row & 7)) * 8)];
        }

        #pragma unroll
        for (int ks = 0; ks < 2; ++ks)
            #pragma unroll
            for (int m = 0; m < 4; ++m)
                #pragma unroll
                for (int n = 0; n < 4; ++n)
                    acc[m][n] = __builtin_amdgcn_mfma_f32_16x16x32_bf16(
                        a[m][ks], b[n][ks], acc[m][n], 0, 0, 0);
        __syncthreads();
    }

    // ---- epilogue ----
    // C/D layout: col = lane&15, row = (lane>>4)*4 + reg   [m89]
    float cs[4] = {0.f, 0.f, 0.f, 0.f};
    #pragma unroll
    for (int m = 0; m < 4; ++m) {
        #pragma unroll
        for (int r = 0; r < 4; ++r) {
            const int grow = brow + wr * 64 + m * 16 + kg * 4 + r;
            float rs = 0.f;
            #pragma unroll
            for (int n = 0; n < 4; ++n) {
                const int gcol = bcol + wc * 64 + n * 16 + lr;
                const float s = acc[m][n][r];
                if (posT && gcol == (grow ^ 2048)) { P[grow] = s; P[gcol] = s; }
                float e = __expf(TINV * (s - 1.0f));
                if (diag && gcol == grow) e = 0.f;
                rs += e;
                if (!diag) cs[n] += e;
            }
            rs += __shfl_xor(rs, 1);
            rs += __shfl_xor(rs, 2);
            rs += __shfl_xor(rs, 4);
            rs += __shfl_xor(rs, 8);
            if (lr == 0) atomicAdd(&S[grow], rs);
        }
    }
    if (!diag) {
        #pragma unroll
        for (int n = 0; n < 4; ++n) {
            cs[n] += __shfl_xor(cs[n], 16);
            cs[n] += __shfl_xor(cs[n], 32);
            if (kg == 0)
                atomicAdd(&S[bcol + wc * 64 + n * 16 + lr], cs[n]);
        }
    }

    // ---- fused final: last block to finish reduces S,P -> loss ----
    __threadfence();            // make this block's S/P writes device-visible
    __syncthreads();            // all waves' writes precede the counter inc
    if (tid == 0) {
        unsigned old = atomicAdd(ctr, 1u);
        s_done = (old == NBLK - 1u);
    }
    __syncthreads();
    if (!s_done) return;
    __threadfence();            // acquire side

    float local = 0.f;
    for (int r = tid; r < NROWS; r += 256) {
        float Sv = __hip_atomic_load(&S[r], __ATOMIC_RELAXED,
                                     __HIP_MEMORY_SCOPE_AGENT);
        float Pv = __hip_atomic_load(&P[r], __ATOMIC_RELAXED,
                                     __HIP_MEMORY_SCOPE_AGENT);
        local += TINV + logf(Sv) - TINV * Pv;
    }
    #pragma unroll
    for (int m = 32; m; m >>= 1) local += __shfl_xor(local, m);
    if (lane == 0) red[wid] = local;
    __syncthreads();
    if (tid == 0)
        out[0] = (red[0] + red[1] + red[2] + red[3]) * (1.0f / NROWS);
}

// ---------------------------------------------------------------------------
extern "C" void kernel_launch(void* const* d_in, const int* in_sizes, int n_in,
                              void* d_out, int out_size, void* d_ws, size_t ws_size,
                              hipStream_t stream) {
    const float* feat = (const float*)d_in[0];

    u16*      fb  = (u16*)d_ws;                                      // 4 MB
    float*    S   = (float*)((char*)d_ws + (size_t)NROWS * DIM * 2); // 16 KB
    float*    P   = S + NROWS;                                       // 16 KB
    unsigned* ctr = (unsigned*)(P + NROWS);

    k_norm<<<NROWS / 4, 256, 0, stream>>>(feat, fb, S, ctr);
    k_gemm<<<NBLK, 256, 0, stream>>>(fb, S, P, ctr, (float*)d_out);
}

// Round 5
// 92.887 us; speedup vs baseline: 1.2876x; 1.2876x over previous
//
#include <hip/hip_runtime.h>
#include <hip/hip_bf16.h>

typedef unsigned short u16;
typedef __attribute__((ext_vector_type(8))) short short8;
typedef __attribute__((ext_vector_type(4))) float f32x4;

#define NROWS 4096
#define DIM   512
#define TINV  10.0f   // 1/temperature
#define NTILE 64      // 4096/64
#define NBLK  2080    // NTILE*(NTILE+1)/2

// round-to-nearest-even f32 -> bf16 bits
__device__ __forceinline__ u16 f2bf(float x) {
    unsigned u = __float_as_uint(x);
    unsigned r = (u + 0x7FFFu + ((u >> 16) & 1u)) >> 16;
    return (u16)r;
}

// ---------------------------------------------------------------------------
// Kernel 1: L2-normalize rows -> bf16; zero the S accumulator.
// grid = 1024 x 256 (4 rows/block, 1 wave/row)
// ---------------------------------------------------------------------------
__global__ __launch_bounds__(256) void k_norm(const float* __restrict__ in,
                                              u16* __restrict__ out,
                                              float* __restrict__ S) {
    const int row  = blockIdx.x * 4 + (threadIdx.x >> 6);
    const int lane = threadIdx.x & 63;
    if (threadIdx.x < 4) S[blockIdx.x * 4 + threadIdx.x] = 0.f;

    const float* rp = in + (size_t)row * DIM;
    float4 v0 = ((const float4*)rp)[lane];
    float4 v1 = ((const float4*)rp)[lane + 64];

    float ssq = v0.x*v0.x + v0.y*v0.y + v0.z*v0.z + v0.w*v0.w
              + v1.x*v1.x + v1.y*v1.y + v1.z*v1.z + v1.w*v1.w;
    #pragma unroll
    for (int m = 32; m; m >>= 1) ssq += __shfl_xor(ssq, m);

    const float scale = 1.0f / fmaxf(sqrtf(ssq), 1e-12f);

    u16* op = out + (size_t)row * DIM;
    ((ushort4*)op)[lane] = make_ushort4(
        f2bf(v0.x * scale), f2bf(v0.y * scale),
        f2bf(v0.z * scale), f2bf(v0.w * scale));
    ((ushort4*)op)[lane + 64] = make_ushort4(
        f2bf(v1.x * scale), f2bf(v1.y * scale),
        f2bf(v1.z * scale), f2bf(v1.w * scale));
}

// ---------------------------------------------------------------------------
// Kernel 2: upper-triangular 64x64 tiles of sim = f f^T (2080 blocks).
// Small tiles => ~8 co-resident blocks/CU for latency hiding (round-4 lesson:
// 528x128-tiles gave 2 blocks/CU, occupancy 14%, latency-bound at 5% MfmaUtil).
//  - diag tile  (br==bc): row-sums only (mask diagonal), B aliases A in LDS
//  - off-diag   (br< bc): row-sums -> S[grow], col-sums -> S[gcol]
//  - positive pairs live in tiles bc == br^32: write P[grow] and P[gcol]
// BK=64, XOR-swizzled LDS (chunk ^= row&7), pre-swizzled global source,
// linear global_load_lds dest, swizzled ds_read_b128.   [m97/m173 pattern]
// 4 waves in 2x2; each wave owns a 32x32 output sub-tile (2x2 16x16 frags).
// ---------------------------------------------------------------------------
__device__ __forceinline__ void gload_lds16(const u16* g, u16* l) {
    __builtin_amdgcn_global_load_lds(
        (const __attribute__((address_space(1))) void*)g,
        (__attribute__((address_space(3))) void*)l, 16, 0, 0);
}

__global__ __launch_bounds__(256) void k_gemm(const u16* __restrict__ fb,
                                              float* __restrict__ S,
                                              float* __restrict__ P) {
    // --- decode triangular tile index: off(b) = b*(129-b)/2 ---
    const int t = blockIdx.x;
    int br = (int)((129.0f - sqrtf(16641.0f - 8.0f * (float)t)) * 0.5f);
    br = br < 0 ? 0 : (br > 63 ? 63 : br);
    while (br * (129 - br) / 2 > t) --br;
    while ((br + 1) * (128 - br) / 2 <= t) ++br;
    const int bc = br + (t - br * (129 - br) / 2);

    const bool diag = (br == bc);
    const bool posT = (bc == (br ^ 32));       // tile holding positive pairs

    __shared__ u16 lA[64 * 64];
    __shared__ u16 lB[64 * 64];

    const int tid  = threadIdx.x;
    const int lane = tid & 63;
    const int wid  = tid >> 6;
    const int wr   = wid >> 1;                 // 32-row slab
    const int wc   = wid & 1;                  // 32-col slab
    const int brow = br * 64;
    const int bcol = bc * 64;
    const int lr   = lane & 15;
    const int kg   = lane >> 4;

    f32x4 acc[2][2];
    #pragma unroll
    for (int m = 0; m < 2; ++m)
        #pragma unroll
        for (int n = 0; n < 2; ++n)
            acc[m][n] = (f32x4){0.f, 0.f, 0.f, 0.f};

    const u16* Bsrc = diag ? lA : lB;

    for (int kk = 0; kk < DIM; kk += 64) {
        // ---- stage: 64 rows x 64 elems = 8 KB = 512 chunks of 16B ----
        #pragma unroll
        for (int i = 0; i < 2; ++i) {
            const int q  = tid + i * 256;        // chunk id 0..511
            const int r  = q >> 3;               // tile row 0..63
            const int c  = q & 7;                // dest chunk col
            const int sc = c ^ (r & 7);          // swizzled source chunk
            gload_lds16(fb + (size_t)(brow + r) * DIM + kk + sc * 8, lA + q * 8);
        }
        if (!diag) {
            #pragma unroll
            for (int i = 0; i < 2; ++i) {
                const int q  = tid + i * 256;
                const int r  = q >> 3;
                const int c  = q & 7;
                const int sc = c ^ (r & 7);
                gload_lds16(fb + (size_t)(bcol + r) * DIM + kk + sc * 8, lB + q * 8);
            }
        }
        __syncthreads();

        short8 a[2][2], b[2][2];
        #pragma unroll
        for (int m = 0; m < 2; ++m) {
            const int row = wr * 32 + m * 16 + lr;
            #pragma unroll
            for (int ks = 0; ks < 2; ++ks)
                a[m][ks] = *(const short8*)
                    &lA[row * 64 + (((ks * 4 + kg) ^ (row & 7)) * 8)];
        }
        #pragma unroll
        for (int n = 0; n < 2; ++n) {
            const int row = wc * 32 + n * 16 + lr;
            #pragma unroll
            for (int ks = 0; ks < 2; ++ks)
                b[n][ks] = *(const short8*)
                    &Bsrc[row * 64 + (((ks * 4 + kg) ^ (row & 7)) * 8)];
        }

        #pragma unroll
        for (int ks = 0; ks < 2; ++ks)
            #pragma unroll
            for (int m = 0; m < 2; ++m)
                #pragma unroll
                for (int n = 0; n < 2; ++n)
                    acc[m][n] = __builtin_amdgcn_mfma_f32_16x16x32_bf16(
                        a[m][ks], b[n][ks], acc[m][n], 0, 0, 0);
        __syncthreads();
    }

    // ---- epilogue ----
    // C/D layout: col = lane&15, row = (lane>>4)*4 + reg   [m89]
    float cs[2] = {0.f, 0.f};
    #pragma unroll
    for (int m = 0; m < 2; ++m) {
        #pragma unroll
        for (int r = 0; r < 2 * 2; ++r) {
            ;
        }
    }
    #pragma unroll
    for (int m = 0; m < 2; ++m) {
        #pragma unroll
        for (int r = 0; r < 4; ++r) {
            const int grow = brow + wr * 32 + m * 16 + kg * 4 + r;
            float rs = 0.f;
            #pragma unroll
            for (int n = 0; n < 2; ++n) {
                const int gcol = bcol + wc * 32 + n * 16 + lr;
                const float s = acc[m][n][r];
                if (posT && gcol == (grow ^ 2048)) { P[grow] = s; P[gcol] = s; }
                float e = __expf(TINV * (s - 1.0f));
                if (diag && gcol == grow) e = 0.f;
                rs += e;
                if (!diag) cs[n] += e;
            }
            rs += __shfl_xor(rs, 1);
            rs += __shfl_xor(rs, 2);
            rs += __shfl_xor(rs, 4);
            rs += __shfl_xor(rs, 8);
            if (lr == 0) atomicAdd(&S[grow], rs);
        }
    }
    if (!diag) {
        #pragma unroll
        for (int n = 0; n < 2; ++n) {
            cs[n] += __shfl_xor(cs[n], 16);
            cs[n] += __shfl_xor(cs[n], 32);
            if (kg == 0)
                atomicAdd(&S[bcol + wc * 32 + n * 16 + lr], cs[n]);
        }
    }
}

// ---------------------------------------------------------------------------
// Kernel 3: loss = mean_i (1/T + log S_i - P_i/T)
// ---------------------------------------------------------------------------
__global__ __launch_bounds__(1024) void k_final(const float* __restrict__ S,
                                                const float* __restrict__ P,
                                                float* __restrict__ out) {
    __shared__ float red[1024];
    float local = 0.f;
    #pragma unroll
    for (int i = 0; i < 4; ++i) {
        const int r = threadIdx.x + i * 1024;
        local += TINV + logf(S[r]) - TINV * P[r];
    }
    red[threadIdx.x] = local;
    __syncthreads();
    #pragma unroll
    for (int s = 512; s; s >>= 1) {
        if (threadIdx.x < s) red[threadIdx.x] += red[threadIdx.x + s];
        __syncthreads();
    }
    if (threadIdx.x == 0) out[0] = red[0] * (1.0f / NROWS);
}

// ---------------------------------------------------------------------------
extern "C" void kernel_launch(void* const* d_in, const int* in_sizes, int n_in,
                              void* d_out, int out_size, void* d_ws, size_t ws_size,
                              hipStream_t stream) {
    const float* feat = (const float*)d_in[0];

    u16*   fb = (u16*)d_ws;                                      // 4 MB
    float* S  = (float*)((char*)d_ws + (size_t)NROWS * DIM * 2); // 16 KB
    float* P  = S + NROWS;                                       // 16 KB

    k_norm<<<NROWS / 4, 256, 0, stream>>>(feat, fb, S);
    k_gemm<<<NBLK, 256, 0, stream>>>(fb, S, P);
    k_final<<<1, 1024, 0, stream>>>(S, P, (float*)d_out);
}